// Round 17
// baseline (857.653 us; speedup 1.0000x reference)
//
#include <hip/hip_runtime.h>
#include <hip/hip_bf16.h>

// OrbitalGenerator: 1024 independent [128x256] slices through a 4-layer MPNN.
// One block per orbital, 512 threads (8 waves), wave w owns rows w*16..w*16+16
// END-TO-END (LN1, GEMM1 m-tile, MSG rows, LN2 stats, GEMM2). (512,2) regime.
// R17 = R10 (651us best) with ROW-OWNERSHIP MSG:
//  - MSG: wave computes msg[w16..w16+16][all 256 cols] by looping 8 heads
//    (A = ewbf i-tile 'wave', B = VBUF valsT slices). msg rows are then
//    wave-PRIVATE -> no barrier before GEMM2's tanh read.
//  - LN2 stats wave-local (in-register across heads + one 16-lane ladder);
//    ln2s LDS buffer, 8-head combine, meansel dance all deleted.
//  - valsT in its own VBUF (drops R10's hoist-fence barrier). 3 barriers/layer.
// No manual prefetch (R16 lesson: compiler already pipelines unrolled loops).

#define O_TOT 1024

typedef __bf16 bf16x8 __attribute__((ext_vector_type(8)));
typedef float f32x4 __attribute__((ext_vector_type(4)));

static __device__ __forceinline__ unsigned short f2bf(float f) {
  __bf16 b = (__bf16)f;
  unsigned short u;
  __builtin_memcpy(&u, &b, 2);
  return u;
}
static __device__ __forceinline__ float ftanh(float x) {
  float e = __expf(2.f * x);
  return 1.f - 2.f * __builtin_amdgcn_rcpf(e + 1.f);
}

struct alignas(8) US4 { unsigned short a, b, c, d; };

// XOR swizzles with 2 row bits -> 16 distinct 16B slots per 16 consecutive rows.
static __device__ __forceinline__ int swzA(int row, int cb) {  // [128][512B]
  return row * 512 + (cb ^ ((row & 7) << 4) ^ (((row >> 3) & 1) << 5));
}
static __device__ __forceinline__ int swzV(int row, int cb) {  // [256][256B]
  return row * 256 + (cb ^ ((row & 7) << 4) ^ (((row >> 3) & 1) << 5));
}

// ---------------- setup kernels (identical to R10) ----------------

__global__ void k_orbmap(const int* __restrict__ charges, const int* __restrict__ n_up_p,
                         const int* __restrict__ n_down_p, int* __restrict__ orb_nuc,
                         int* __restrict__ orb_t) {
  __shared__ int off[129];
  __shared__ int prec[128];
  int tid = threadIdx.x;
  if (tid == 0) {
    int a = 0;
    for (int n = 0; n < 128; ++n) { off[n] = a; a += charges[n]; }
    off[128] = a;
  }
  if (tid < 128) prec[tid] = charges[tid] * (charges[tid] - 1) / 2;
  __syncthreads();
  int nu = *n_up_p, nd = *n_down_p;
  for (int o = tid; o < O_TOT; o += 256) {
    int e;
    if (o < nu) e = o;
    else if (o < 512) e = o + nd;
    else if (o < 512 + nd) e = o + nu - 512;
    else e = o;
    int nn = -1, tt = 0;
    for (int n = 0; n < 128; ++n) {
      if (e >= off[n] && e < off[n + 1]) { nn = n; tt = prec[n] + (e - off[n]); }
    }
    orb_nuc[o] = nn;
    orb_t[o] = tt;
  }
}

// ewbf fragment-major: [l][h][mt(8)][k0(4)][lane(64)][j(8)] bf16 (1MB total).
__global__ void k_ew(const float* __restrict__ coords, const float* __restrict__ W_edge,
                     unsigned short* __restrict__ ewbf) {
  int i = blockIdx.x, j = threadIdx.x;
  float dx = coords[i * 3 + 0] - coords[j * 3 + 0];
  float dy = coords[i * 3 + 1] - coords[j * 3 + 1];
  float dz = coords[i * 3 + 2] - coords[j * 3 + 2];
  float norm = sqrtf(dx * dx + dy * dy + dz * dz + 1e-12f);
  float inv = 1.f / (1.f + norm);
  float e[7];
  e[0] = dx * inv; e[1] = dy * inv; e[2] = dz * inv;
  e[3] = log1pf(norm);
  e[4] = 1.f / (1.f + expf(-(norm - 2.f)));
  e[5] = 1.f / (1.f + expf(-(norm - 4.f)));
  e[6] = 1.f / (1.f + expf(-(norm - 6.f)));
  const int mt = i >> 4, l16 = i & 15;
  const int k0 = j >> 5, jo = j & 31;
  const int lane = (jo >> 3) * 16 + l16, jj = jo & 7;
  for (int l = 0; l < 4; ++l)
    for (int h = 0; h < 8; ++h) {
      float s = 0.f;
      for (int k = 0; k < 7; ++k) s += e[k] * W_edge[(l * 7 + k) * 8 + h];
      ewbf[(((((l * 8 + h) * 8 + mt) * 4 + k0) * 64) + lane) * 8 + jj] = f2bf(s);
    }
}

// WvTf/WoTf fragment-major: [l][gt(16)][k0(8)][lane(64)][jj(8)] bf16.
__global__ void k_wt(const float* __restrict__ Wv, const float* __restrict__ Wo,
                     unsigned short* __restrict__ WvTf, unsigned short* __restrict__ WoTf) {
  int idx = blockIdx.x * 256 + threadIdx.x;  // 4*65536
  const int l = idx >> 16, rem = idx & 65535;
  const int jj = rem & 7, lane = (rem >> 3) & 63, k0 = (rem >> 9) & 7, gt = rem >> 12;
  const int g = gt * 16 + (lane & 15);
  const int f = k0 * 32 + (lane >> 4) * 8 + jj;
  const int src = l * 65536 + f * 256 + g;
  WvTf[idx] = f2bf(Wv[src]);
  WoTf[idx] = f2bf(Wo[src]);
}

// nucbT[l][g][i] = nuc_feats[i,:] @ W_nuc[l][:,g]  (fp32, transposed)
__global__ void k_nucbT(const float* __restrict__ nuc_feats, const float* __restrict__ W_nuc,
                        float* __restrict__ nucbT) {
  int b = blockIdx.x;  // l*128 + i
  int l = b >> 7, i = b & 127;
  int g = threadIdx.x;
  __shared__ float row[256];
  row[g] = nuc_feats[i * 256 + g];
  __syncthreads();
  const float* Wn = W_nuc + l * 65536;
  float s = 0.f;
  for (int f = 0; f < 256; ++f) s += row[f] * Wn[f * 256 + g];
  nucbT[(l * 256 + g) * 128 + i] = s;
}

// ---------------- fused main kernel ----------------

__global__ __launch_bounds__(512, 2) void k_main(
    float* __restrict__ feats,                // d_out [1024][128][256] fp32
    const float* __restrict__ W_orb,          // [136][256]
    const unsigned short* __restrict__ WvTf,  // fragment-major (see k_wt)
    const unsigned short* __restrict__ WoTf,  // fragment-major
    const unsigned short* __restrict__ ewbf,  // fragment-major (see k_ew)
    const float* __restrict__ nucbT,          // [4][256][128] fp32
    const int* __restrict__ orb_nuc, const int* __restrict__ orb_t) {
  __shared__ char SB[65536];    // h -> msg (wave-private rows in both uses)
  __shared__ char VBUF[65536];  // valsT
  __shared__ float red1[8];     // LN1 max-var partials
  __shared__ float red2[8];     // LN2 max-var partials

  const int o = blockIdx.x;
  const int tid = threadIdx.x;
  const int wave = tid >> 6;
  const int lane = tid & 63;
  const int l16 = lane & 15;
  const int kgrp = (lane >> 4) << 3;  // A/B fragment k-offset: 0,8,16,24
  const int rgrp = (lane >> 4) << 2;  // D fragment row group: 0,4,8,12
  const int w16 = wave * 16;          // this wave's 16 rows

  const int nn = orb_nuc[o];
  const int tt = orb_t[o];
  float* fo = feats + (size_t)o * 32768;

  // feats residual: fr[gt][r] = feats[w16+rgrp+r][gt*16+l16]  (64 f32, AGPR)
  f32x4 fr[16];
#pragma unroll
  for (int gt = 0; gt < 16; ++gt) {
    f32x4 v = {0.f, 0.f, 0.f, 0.f};
#pragma unroll
    for (int r = 0; r < 4; ++r)
      if (w16 + rgrp + r == nn) v[r] = W_orb[tt * 256 + gt * 16 + l16];
    fr[gt] = v;
  }

#pragma unroll 1
  for (int l = 0; l < 4; ++l) {
    // ---- P1: LN1 (wave-local): stats from fr, centered h -> private SB rows,
    //      A-fragments hoisted back (in-wave LDS ordering, no barrier) ----
    bf16x8 A[8];
    {
      float s[4] = {0, 0, 0, 0}, q[4] = {0, 0, 0, 0};
#pragma unroll
      for (int gt = 0; gt < 16; ++gt)
#pragma unroll
        for (int r = 0; r < 4; ++r) {
          float v = fr[gt][r];
          s[r] += v; q[r] += v * v;
        }
#pragma unroll
      for (int of = 1; of < 16; of <<= 1)
#pragma unroll
        for (int r = 0; r < 4; ++r) {
          s[r] += __shfl_xor(s[r], of);
          q[r] += __shfl_xor(q[r], of);
        }
      float mean[4], maxv = 0.f;
#pragma unroll
      for (int r = 0; r < 4; ++r) {
        mean[r] = s[r] * (1.f / 256.f);
        const float var = q[r] * (1.f / 256.f) - mean[r] * mean[r];
        maxv = fmaxf(maxv, var);
      }
      maxv = fmaxf(maxv, __shfl_xor(maxv, 16));
      maxv = fmaxf(maxv, __shfl_xor(maxv, 32));
      if (lane == 0) red1[wave] = maxv;
#pragma unroll
      for (int gt = 0; gt < 16; ++gt)
#pragma unroll
        for (int r = 0; r < 4; ++r)
          *(unsigned short*)(SB + swzA(w16 + rgrp + r, (gt * 16 + l16) * 2)) =
              f2bf(fr[gt][r] - mean[r]);
#pragma unroll
      for (int k0 = 0; k0 < 8; ++k0)
        A[k0] = *(const bf16x8*)(SB + swzA(w16 + l16, (k0 * 32 + kgrp) * 2));
    }
    __syncthreads();  // B1: red1 ready; all prior-layer VBUF reads fenced

    // ---- P2: GEMM1: valsT[g][n] = rstd*(h @ W_val) -> VBUF (R10 pattern) ----
    {
      float mv = red1[0];
#pragma unroll
      for (int w = 1; w < 8; ++w) mv = fmaxf(mv, red1[w]);
      const float rstd = rsqrtf(mv + 1.f);
      const unsigned short* Wl = WvTf + l * 65536 + lane * 8;
#pragma unroll
      for (int gt = 0; gt < 16; ++gt) {
        f32x4 acc = {0.f, 0.f, 0.f, 0.f};
        bf16x8 b[4];
#pragma unroll
        for (int k0 = 0; k0 < 4; ++k0)
          b[k0] = *(const bf16x8*)(Wl + (gt * 8 + k0) * 512);
#pragma unroll
        for (int k0 = 0; k0 < 4; ++k0)
          acc = __builtin_amdgcn_mfma_f32_16x16x32_bf16(A[k0], b[k0], acc, 0, 0, 0);
#pragma unroll
        for (int k0 = 0; k0 < 4; ++k0)
          b[k0] = *(const bf16x8*)(Wl + (gt * 8 + k0 + 4) * 512);
#pragma unroll
        for (int k0 = 0; k0 < 4; ++k0)
          acc = __builtin_amdgcn_mfma_f32_16x16x32_bf16(A[k0 + 4], b[k0], acc, 0, 0, 0);
        const int gg = gt * 16 + l16;
        US4 ov{f2bf(acc[0] * rstd), f2bf(acc[1] * rstd), f2bf(acc[2] * rstd),
               f2bf(acc[3] * rstd)};
        *(US4*)(VBUF + swzV(gg, (w16 + rgrp) * 2)) = ov;
      }
    }
    __syncthreads();  // B2: valsT complete

    // ---- P3: MSG row-ownership: msg[w16..w16+16][all 256 cols], 8 heads;
    //      LN2 stats accumulate wave-locally in registers ----
    float mean2[4];
    {
      float sacc[4] = {0, 0, 0, 0}, qacc[4] = {0, 0, 0, 0};
      const float* nbT = nucbT + l * 32768;
#pragma unroll
      for (int h = 0; h < 8; ++h) {
        const unsigned short* ewh =
            ewbf + (((l * 8 + h) * 8 + wave) * 4 * 64) * 8 + lane * 8;
        bf16x8 a[4];
#pragma unroll
        for (int k0 = 0; k0 < 4; ++k0)
          a[k0] = *(const bf16x8*)(ewh + k0 * 512);
        bf16x8 VB0[4], VB1[4];
#pragma unroll
        for (int k0 = 0; k0 < 4; ++k0) {
          VB0[k0] = *(const bf16x8*)(VBUF + swzV(h * 32 + l16, (k0 * 32 + kgrp) * 2));
          VB1[k0] = *(const bf16x8*)(VBUF + swzV(h * 32 + 16 + l16, (k0 * 32 + kgrp) * 2));
        }
        f32x4 acc0 = {0.f, 0.f, 0.f, 0.f}, acc1 = {0.f, 0.f, 0.f, 0.f};
#pragma unroll
        for (int k0 = 0; k0 < 4; ++k0) {
          acc0 = __builtin_amdgcn_mfma_f32_16x16x32_bf16(a[k0], VB0[k0], acc0, 0, 0, 0);
          acc1 = __builtin_amdgcn_mfma_f32_16x16x32_bf16(a[k0], VB1[k0], acc1, 0, 0, 0);
        }
        const int f0 = h * 32 + l16, f1 = f0 + 16;
        const f32x4 nb0 = *(const f32x4*)(nbT + f0 * 128 + w16 + rgrp);
        const f32x4 nb1 = *(const f32x4*)(nbT + f1 * 128 + w16 + rgrp);
#pragma unroll
        for (int r = 0; r < 4; ++r) {
          const float v0 = acc0[r] + nb0[r];
          const float v1 = acc1[r] + nb1[r];
          *(unsigned short*)(SB + swzA(w16 + rgrp + r, f0 * 2)) = f2bf(v0);
          *(unsigned short*)(SB + swzA(w16 + rgrp + r, f1 * 2)) = f2bf(v1);
          sacc[r] += v0 + v1;
          qacc[r] += v0 * v0 + v1 * v1;
        }
      }
      // finalize stats: one 16-lane ladder (rows rgrp..rgrp+3 per kgrp group)
#pragma unroll
      for (int of = 1; of < 16; of <<= 1)
#pragma unroll
        for (int r = 0; r < 4; ++r) {
          sacc[r] += __shfl_xor(sacc[r], of);
          qacc[r] += __shfl_xor(qacc[r], of);
        }
      float maxv = 0.f;
#pragma unroll
      for (int r = 0; r < 4; ++r) {
        mean2[r] = sacc[r] * (1.f / 256.f);
        maxv = fmaxf(maxv, qacc[r] * (1.f / 256.f) - mean2[r] * mean2[r]);
      }
      maxv = fmaxf(maxv, __shfl_xor(maxv, 16));
      maxv = fmaxf(maxv, __shfl_xor(maxv, 32));
      if (lane == 0) red2[wave] = maxv;
    }
    __syncthreads();  // B3: red2 ready (msg rows are wave-private, no fence)

    // ---- P4: tanh A2-build (own msg row) + GEMM2 (R10 pattern, fr seeds) ----
    {
      float mv = red2[0];
#pragma unroll
      for (int w = 1; w < 8; ++w) mv = fmaxf(mv, red2[w]);
      const float rstd2 = rsqrtf(mv + 1.f);
      // mean of row w16+l16: held (as mean2[l16&3]) by lanes with rgrp=(l16>>2)*4
      const int rsel = l16 & 3;
      const float mcand = (rsel == 0)   ? mean2[0]
                          : (rsel == 1) ? mean2[1]
                          : (rsel == 2) ? mean2[2]
                                        : mean2[3];
      const float mn = __shfl(mcand, ((l16 >> 2) << 4) + l16);

      bf16x8 A2[8];
#pragma unroll
      for (int k0 = 0; k0 < 8; ++k0) {
        bf16x8 raw = *(const bf16x8*)(SB + swzA(w16 + l16, (k0 * 32 + kgrp) * 2));
        bf16x8 t;
#pragma unroll
        for (int j = 0; j < 8; ++j)
          t[j] = (__bf16)ftanh(((float)raw[j] - mn) * rstd2);
        A2[k0] = t;
      }

      const unsigned short* Wl = WoTf + l * 65536 + lane * 8;
#pragma unroll
      for (int gt = 0; gt < 16; ++gt) {
        f32x4 acc = fr[gt];
        bf16x8 b[4];
#pragma unroll
        for (int k0 = 0; k0 < 4; ++k0)
          b[k0] = *(const bf16x8*)(Wl + (gt * 8 + k0) * 512);
#pragma unroll
        for (int k0 = 0; k0 < 4; ++k0)
          acc = __builtin_amdgcn_mfma_f32_16x16x32_bf16(A2[k0], b[k0], acc, 0, 0, 0);
#pragma unroll
        for (int k0 = 0; k0 < 4; ++k0)
          b[k0] = *(const bf16x8*)(Wl + (gt * 8 + k0 + 4) * 512);
#pragma unroll
        for (int k0 = 0; k0 < 4; ++k0)
          acc = __builtin_amdgcn_mfma_f32_16x16x32_bf16(A2[k0 + 4], b[k0], acc, 0, 0, 0);
        fr[gt] = acc;
      }
    }
    // no end-of-layer barrier: P4 reads only this wave's private msg rows;
    // next-layer P1 writes only this wave's private rows (in-wave ordering);
    // VBUF rewrite is fenced by next layer's B1.
  }

  // ---- final store: direct from fr (64B segments per l16 group) ----
#pragma unroll
  for (int gt = 0; gt < 16; ++gt)
#pragma unroll
    for (int r = 0; r < 4; ++r)
      fo[(w16 + rgrp + r) * 256 + gt * 16 + l16] = fr[gt][r];
}

// ---------------- launcher ----------------

extern "C" void kernel_launch(void* const* d_in, const int* in_sizes, int n_in,
                              void* d_out, int out_size, void* d_ws, size_t ws_size,
                              hipStream_t stream) {
  const float* coords = (const float*)d_in[0];
  const int* charges = (const int*)d_in[1];
  const int* n_up = (const int*)d_in[3];
  const int* n_down = (const int*)d_in[4];
  const float* nuc_feats = (const float*)d_in[5];
  const float* W_orb = (const float*)d_in[7];
  const float* W_edge = (const float*)d_in[8];
  const float* W_val = (const float*)d_in[9];
  const float* W_nuc = (const float*)d_in[10];
  const float* W_out = (const float*)d_in[11];
  float* out = (float*)d_out;

  char* ws = (char*)d_ws;
  int* orb_nuc = (int*)ws;                                        // 4KB
  int* orb_t = (int*)(ws + 4096);                                 // 4KB
  unsigned short* ewbf = (unsigned short*)(ws + 8192);            // 1MB
  unsigned short* WvTf = (unsigned short*)(ws + 8192 + 1048576);  // 512KB
  unsigned short* WoTf = WvTf + 262144;                           // 512KB
  float* nucbT = (float*)(ws + 8192 + 1048576 + 1048576);         // 512KB

  k_orbmap<<<dim3(1), dim3(256), 0, stream>>>(charges, n_up, n_down, orb_nuc, orb_t);
  k_ew<<<dim3(128), dim3(128), 0, stream>>>(coords, W_edge, ewbf);
  k_wt<<<dim3(1024), dim3(256), 0, stream>>>(W_val, W_out, WvTf, WoTf);
  k_nucbT<<<dim3(512), dim3(256), 0, stream>>>(nuc_feats, W_nuc, nucbT);
  k_main<<<dim3(O_TOT), dim3(512), 0, stream>>>(out, W_orb, WvTf, WoTf, ewbf, nucbT,
                                                orb_nuc, orb_t);
}

// Round 18
// 651.039 us; speedup vs baseline: 1.3174x; 1.3174x over previous
//
#include <hip/hip_runtime.h>
#include <hip/hip_bf16.h>

// OrbitalGenerator: 1024 independent [128x256] slices through a 4-layer MPNN.
// One block per orbital, 512 threads (8 waves). Wave w owns rows w*16..w*16+16.
// R18 = exact revert to R10 (651us, session best). R11-R17 falsified every
// structural variant: occupancy is hard-capped at 2 waves/SIMD by the
// 128-arch + 64-AGPR footprint (all register-shrink attempts spilled via the
// allocator's 64/64 split); manual prefetch and barrier restructures all
// regressed (compiler already pipelines the unrolled phases). R10's traffic
// is at the ideal footprint (75MB FETCH / 200MB WRITE).

#define O_TOT 1024

typedef __bf16 bf16x8 __attribute__((ext_vector_type(8)));
typedef float f32x4 __attribute__((ext_vector_type(4)));

static __device__ __forceinline__ unsigned short f2bf(float f) {
  __bf16 b = (__bf16)f;
  unsigned short u;
  __builtin_memcpy(&u, &b, 2);
  return u;
}
static __device__ __forceinline__ float ftanh(float x) {
  float e = __expf(2.f * x);
  return 1.f - 2.f * __builtin_amdgcn_rcpf(e + 1.f);
}

struct alignas(8) US4 { unsigned short a, b, c, d; };

// XOR swizzles with 2 row bits -> 16 distinct 16B slots per 16 consecutive rows.
static __device__ __forceinline__ int swzA(int row, int cb) {  // [128][512B]
  return row * 512 + (cb ^ ((row & 7) << 4) ^ (((row >> 3) & 1) << 5));
}
static __device__ __forceinline__ int swzV(int row, int cb) {  // [256][256B]
  return row * 256 + (cb ^ ((row & 7) << 4) ^ (((row >> 3) & 1) << 5));
}

// ---------------- setup kernels ----------------

__global__ void k_orbmap(const int* __restrict__ charges, const int* __restrict__ n_up_p,
                         const int* __restrict__ n_down_p, int* __restrict__ orb_nuc,
                         int* __restrict__ orb_t) {
  __shared__ int off[129];
  __shared__ int prec[128];
  int tid = threadIdx.x;
  if (tid == 0) {
    int a = 0;
    for (int n = 0; n < 128; ++n) { off[n] = a; a += charges[n]; }
    off[128] = a;
  }
  if (tid < 128) prec[tid] = charges[tid] * (charges[tid] - 1) / 2;
  __syncthreads();
  int nu = *n_up_p, nd = *n_down_p;
  for (int o = tid; o < O_TOT; o += 256) {
    int e;
    if (o < nu) e = o;
    else if (o < 512) e = o + nd;
    else if (o < 512 + nd) e = o + nu - 512;
    else e = o;
    int nn = -1, tt = 0;
    for (int n = 0; n < 128; ++n) {
      if (e >= off[n] && e < off[n + 1]) { nn = n; tt = prec[n] + (e - off[n]); }
    }
    orb_nuc[o] = nn;
    orb_t[o] = tt;
  }
}

// ewbf fragment-major: [l][h][mt(8)][k0(4)][lane(64)][j(8)] bf16 (1MB total).
// frag (l,h,mt,k0), lane: i = mt*16 + (lane&15), j = k0*32 + (lane>>4)*8 + jj.
__global__ void k_ew(const float* __restrict__ coords, const float* __restrict__ W_edge,
                     unsigned short* __restrict__ ewbf) {
  int i = blockIdx.x, j = threadIdx.x;
  float dx = coords[i * 3 + 0] - coords[j * 3 + 0];
  float dy = coords[i * 3 + 1] - coords[j * 3 + 1];
  float dz = coords[i * 3 + 2] - coords[j * 3 + 2];
  float norm = sqrtf(dx * dx + dy * dy + dz * dz + 1e-12f);
  float inv = 1.f / (1.f + norm);
  float e[7];
  e[0] = dx * inv; e[1] = dy * inv; e[2] = dz * inv;
  e[3] = log1pf(norm);
  e[4] = 1.f / (1.f + expf(-(norm - 2.f)));
  e[5] = 1.f / (1.f + expf(-(norm - 4.f)));
  e[6] = 1.f / (1.f + expf(-(norm - 6.f)));
  const int mt = i >> 4, l16 = i & 15;
  const int k0 = j >> 5, jo = j & 31;
  const int lane = (jo >> 3) * 16 + l16, jj = jo & 7;
  for (int l = 0; l < 4; ++l)
    for (int h = 0; h < 8; ++h) {
      float s = 0.f;
      for (int k = 0; k < 7; ++k) s += e[k] * W_edge[(l * 7 + k) * 8 + h];
      ewbf[(((((l * 8 + h) * 8 + mt) * 4 + k0) * 64) + lane) * 8 + jj] = f2bf(s);
    }
}

// WvTf/WoTf fragment-major: [l][gt(16)][k0(8)][lane(64)][jj(8)] bf16.
// frag (l,gt,k0), lane: g = gt*16 + (lane&15), f = k0*32 + (lane>>4)*8 + jj.
__global__ void k_wt(const float* __restrict__ Wv, const float* __restrict__ Wo,
                     unsigned short* __restrict__ WvTf, unsigned short* __restrict__ WoTf) {
  int idx = blockIdx.x * 256 + threadIdx.x;  // 4*65536
  const int l = idx >> 16, rem = idx & 65535;
  const int jj = rem & 7, lane = (rem >> 3) & 63, k0 = (rem >> 9) & 7, gt = rem >> 12;
  const int g = gt * 16 + (lane & 15);
  const int f = k0 * 32 + (lane >> 4) * 8 + jj;
  const int src = l * 65536 + f * 256 + g;
  WvTf[idx] = f2bf(Wv[src]);
  WoTf[idx] = f2bf(Wo[src]);
}

// nucbT[l][g][i] = nuc_feats[i,:] @ W_nuc[l][:,g]  (fp32, transposed)
__global__ void k_nucbT(const float* __restrict__ nuc_feats, const float* __restrict__ W_nuc,
                        float* __restrict__ nucbT) {
  int b = blockIdx.x;  // l*128 + i
  int l = b >> 7, i = b & 127;
  int g = threadIdx.x;
  __shared__ float row[256];
  row[g] = nuc_feats[i * 256 + g];
  __syncthreads();
  const float* Wn = W_nuc + l * 65536;
  float s = 0.f;
  for (int f = 0; f < 256; ++f) s += row[f] * Wn[f * 256 + g];
  nucbT[(l * 256 + g) * 128 + i] = s;
}

// ---------------- fused main kernel ----------------

__global__ __launch_bounds__(512, 2) void k_main(
    float* __restrict__ feats,                // d_out [1024][128][256] fp32
    const float* __restrict__ W_orb,          // [136][256]
    const unsigned short* __restrict__ WvTf,  // fragment-major (see k_wt)
    const unsigned short* __restrict__ WoTf,  // fragment-major
    const unsigned short* __restrict__ ewbf,  // fragment-major (see k_ew)
    const float* __restrict__ nucbT,          // [4][256][128] fp32
    const int* __restrict__ orb_nuc, const int* __restrict__ orb_t) {
  __shared__ char SB[65536];       // h -> valsT -> msg (reused via barriers)
  __shared__ float2 ln2s[8][128];  // LN2 per-head partials [head][row]{s,ss}
  __shared__ float red[8];

  const int o = blockIdx.x;
  const int tid = threadIdx.x;
  const int wave = tid >> 6;
  const int lane = tid & 63;
  const int l16 = lane & 15;
  const int kgrp = (lane >> 4) << 3;  // A/B fragment k-offset: 0,8,16,24
  const int rgrp = (lane >> 4) << 2;  // D fragment row group: 0,4,8,12
  const int w16 = wave * 16;          // this wave's 16 rows (LN1/GEMM1/GEMM2)

  const int nn = orb_nuc[o];
  const int tt = orb_t[o];
  float* fo = feats + (size_t)o * 32768;

  // feats in registers: fr[gt][r] = feats[w16+rgrp+r][gt*16+l16]  (64 regs)
  f32x4 fr[16];
#pragma unroll
  for (int gt = 0; gt < 16; ++gt) {
    f32x4 v = {0.f, 0.f, 0.f, 0.f};
#pragma unroll
    for (int r = 0; r < 4; ++r)
      if (w16 + rgrp + r == nn) v[r] = W_orb[tt * 256 + gt * 16 + l16];
    fr[gt] = v;
  }

#pragma unroll 1
  for (int l = 0; l < 4; ++l) {
    // ---- LN1 (wave-local): stats from fr, centered h -> private SB rows,
    //      A-fragments hoisted back (in-wave LDS ordering, no barrier) ----
    bf16x8 A[8];
    {
      float s[4] = {0, 0, 0, 0}, q[4] = {0, 0, 0, 0};
#pragma unroll
      for (int gt = 0; gt < 16; ++gt)
#pragma unroll
        for (int r = 0; r < 4; ++r) {
          float v = fr[gt][r];
          s[r] += v; q[r] += v * v;
        }
#pragma unroll
      for (int of = 1; of < 16; of <<= 1)
#pragma unroll
        for (int r = 0; r < 4; ++r) {
          s[r] += __shfl_xor(s[r], of);
          q[r] += __shfl_xor(q[r], of);
        }
      float mean[4], maxv = 0.f;
#pragma unroll
      for (int r = 0; r < 4; ++r) {
        mean[r] = s[r] * (1.f / 256.f);
        const float var = q[r] * (1.f / 256.f) - mean[r] * mean[r];
        maxv = fmaxf(maxv, var);
      }
      maxv = fmaxf(maxv, __shfl_xor(maxv, 16));
      maxv = fmaxf(maxv, __shfl_xor(maxv, 32));
      if (lane == 0) red[wave] = maxv;
#pragma unroll
      for (int gt = 0; gt < 16; ++gt)
#pragma unroll
        for (int r = 0; r < 4; ++r)
          *(unsigned short*)(SB + swzA(w16 + rgrp + r, (gt * 16 + l16) * 2)) =
              f2bf(fr[gt][r] - mean[r]);
#pragma unroll
      for (int k0 = 0; k0 < 8; ++k0)
        A[k0] = *(const bf16x8*)(SB + swzA(w16 + l16, (k0 * 32 + kgrp) * 2));
    }
    __syncthreads();  // B1: all A-frags hoisted + red ready; SB reusable

    // ---- GEMM1: valsT[g][n] = rstd*(h @ W_val); n = wave's 16 rows ----
    {
      float mv = red[0];
#pragma unroll
      for (int w = 1; w < 8; ++w) mv = fmaxf(mv, red[w]);
      const float rstd = rsqrtf(mv + 1.f);
      const unsigned short* Wl = WvTf + (l * 16 * 8 * 64 * 8) + lane * 8;
#pragma unroll
      for (int gt = 0; gt < 16; ++gt) {
        f32x4 acc = {0.f, 0.f, 0.f, 0.f};
        bf16x8 b[4];
#pragma unroll
        for (int k0 = 0; k0 < 4; ++k0)
          b[k0] = *(const bf16x8*)(Wl + (gt * 8 + k0) * 512);
#pragma unroll
        for (int k0 = 0; k0 < 4; ++k0)
          acc = __builtin_amdgcn_mfma_f32_16x16x32_bf16(A[k0], b[k0], acc, 0, 0, 0);
#pragma unroll
        for (int k0 = 0; k0 < 4; ++k0)
          b[k0] = *(const bf16x8*)(Wl + (gt * 8 + k0 + 4) * 512);
#pragma unroll
        for (int k0 = 0; k0 < 4; ++k0)
          acc = __builtin_amdgcn_mfma_f32_16x16x32_bf16(A[k0 + 4], b[k0], acc, 0, 0, 0);
        const int gg = gt * 16 + l16;
        US4 ov{f2bf(acc[0] * rstd), f2bf(acc[1] * rstd), f2bf(acc[2] * rstd),
               f2bf(acc[3] * rstd)};
        *(US4*)(SB + swzV(gg, (w16 + rgrp) * 2)) = ov;
      }
    }
    __syncthreads();  // B2: valsT complete

    // ---- hoist this head's valsT slice (f-rows wave*32..+32, K=128) ----
    bf16x8 B0[4], B1[4];
#pragma unroll
    for (int k0 = 0; k0 < 4; ++k0) {
      B0[k0] = *(const bf16x8*)(SB + swzV(wave * 32 + l16, (k0 * 32 + kgrp) * 2));
      B1[k0] = *(const bf16x8*)(SB + swzV(wave * 32 + 16 + l16, (k0 * 32 + kgrp) * 2));
    }
    __syncthreads();  // B3: all valsT reads done; SB reusable for msg

    // ---- MSG: msg[i][f] = sum_j ew[w][i][j]*valsT[f][j] + nucbT[f][i] ----
    {
      const unsigned short* ewh = ewbf + ((l * 8 + wave) * 8 * 4 * 64 * 8) + lane * 8;
      const float* nbT = nucbT + l * 32768;
      const int f0 = wave * 32 + l16;
      const int f1 = f0 + 16;
#pragma unroll
      for (int mt = 0; mt < 8; ++mt) {
        const int i0 = mt * 16;
        f32x4 acc0 = {0.f, 0.f, 0.f, 0.f}, acc1 = {0.f, 0.f, 0.f, 0.f};
        {
          bf16x8 a0 = *(const bf16x8*)(ewh + (mt * 4 + 0) * 512);
          bf16x8 a1 = *(const bf16x8*)(ewh + (mt * 4 + 1) * 512);
          acc0 = __builtin_amdgcn_mfma_f32_16x16x32_bf16(a0, B0[0], acc0, 0, 0, 0);
          acc1 = __builtin_amdgcn_mfma_f32_16x16x32_bf16(a0, B1[0], acc1, 0, 0, 0);
          acc0 = __builtin_amdgcn_mfma_f32_16x16x32_bf16(a1, B0[1], acc0, 0, 0, 0);
          acc1 = __builtin_amdgcn_mfma_f32_16x16x32_bf16(a1, B1[1], acc1, 0, 0, 0);
        }
        {
          bf16x8 a0 = *(const bf16x8*)(ewh + (mt * 4 + 2) * 512);
          bf16x8 a1 = *(const bf16x8*)(ewh + (mt * 4 + 3) * 512);
          acc0 = __builtin_amdgcn_mfma_f32_16x16x32_bf16(a0, B0[2], acc0, 0, 0, 0);
          acc1 = __builtin_amdgcn_mfma_f32_16x16x32_bf16(a0, B1[2], acc1, 0, 0, 0);
          acc0 = __builtin_amdgcn_mfma_f32_16x16x32_bf16(a1, B0[3], acc0, 0, 0, 0);
          acc1 = __builtin_amdgcn_mfma_f32_16x16x32_bf16(a1, B1[3], acc1, 0, 0, 0);
        }
        const f32x4 nb0 = *(const f32x4*)(nbT + f0 * 128 + i0 + rgrp);
        const f32x4 nb1 = *(const f32x4*)(nbT + f1 * 128 + i0 + rgrp);
        float sp[4], qp[4];
#pragma unroll
        for (int r = 0; r < 4; ++r) {
          const float v0 = acc0[r] + nb0[r];
          const float v1 = acc1[r] + nb1[r];
          *(unsigned short*)(SB + swzA(i0 + rgrp + r, f0 * 2)) = f2bf(v0);
          *(unsigned short*)(SB + swzA(i0 + rgrp + r, f1 * 2)) = f2bf(v1);
          sp[r] = v0 + v1;
          qp[r] = v0 * v0 + v1 * v1;
        }
#pragma unroll
        for (int of = 1; of < 16; of <<= 1)
#pragma unroll
          for (int r = 0; r < 4; ++r) {
            sp[r] += __shfl_xor(sp[r], of);
            qp[r] += __shfl_xor(qp[r], of);
          }
        if (l16 == 0) {
#pragma unroll
          for (int r = 0; r < 4; ++r)
            ln2s[wave][i0 + rgrp + r] = float2{sp[r], qp[r]};
        }
      }
    }
    __syncthreads();  // B4: msg + ln2s ready

    // ---- LN2 combine + GEMM2 with fused tanh A-build (msg rows private) ----
    {
      float s0 = 0.f, q0 = 0.f, s1v = 0.f, q1v = 0.f;
#pragma unroll
      for (int h = 0; h < 8; ++h) {
        const float2 p0 = ln2s[h][lane];
        const float2 p1 = ln2s[h][lane + 64];
        s0 += p0.x; q0 += p0.y;
        s1v += p1.x; q1v += p1.y;
      }
      const float mean_a = s0 * (1.f / 256.f);
      const float mean_b = s1v * (1.f / 256.f);
      float v0 = q0 * (1.f / 256.f) - mean_a * mean_a;
      float v1 = q1v * (1.f / 256.f) - mean_b * mean_b;
      float mv = fmaxf(v0, v1);
#pragma unroll
      for (int of = 1; of < 64; of <<= 1) mv = fmaxf(mv, __shfl_xor(mv, of));
      const float rstd2 = rsqrtf(mv + 1.f);
      const float meansel = (wave >= 4) ? mean_b : mean_a;
      const float mn = __shfl(meansel, ((wave & 3) << 4) + l16);  // mean of row w16+l16

      bf16x8 A2[8];
#pragma unroll
      for (int k0 = 0; k0 < 8; ++k0) {
        bf16x8 raw = *(const bf16x8*)(SB + swzA(w16 + l16, (k0 * 32 + kgrp) * 2));
        bf16x8 t;
#pragma unroll
        for (int j = 0; j < 8; ++j)
          t[j] = (__bf16)ftanh(((float)raw[j] - mn) * rstd2);
        A2[k0] = t;
      }

      const unsigned short* Wl = WoTf + (l * 16 * 8 * 64 * 8) + lane * 8;
#pragma unroll
      for (int gt = 0; gt < 16; ++gt) {
        f32x4 acc = fr[gt];
        bf16x8 b[4];
#pragma unroll
        for (int k0 = 0; k0 < 4; ++k0)
          b[k0] = *(const bf16x8*)(Wl + (gt * 8 + k0) * 512);
#pragma unroll
        for (int k0 = 0; k0 < 4; ++k0)
          acc = __builtin_amdgcn_mfma_f32_16x16x32_bf16(A2[k0], b[k0], acc, 0, 0, 0);
#pragma unroll
        for (int k0 = 0; k0 < 4; ++k0)
          b[k0] = *(const bf16x8*)(Wl + (gt * 8 + k0 + 4) * 512);
#pragma unroll
        for (int k0 = 0; k0 < 4; ++k0)
          acc = __builtin_amdgcn_mfma_f32_16x16x32_bf16(A2[k0 + 4], b[k0], acc, 0, 0, 0);
        fr[gt] = acc;
      }
    }
    // no end-of-layer barrier: GEMM2 read only this wave's private msg rows;
    // next-layer LN1 writes the same private rows (in-wave LDS ordering).
  }

  // ---- final store: direct from fr (64B segments per l16 group) ----
#pragma unroll
  for (int gt = 0; gt < 16; ++gt)
#pragma unroll
    for (int r = 0; r < 4; ++r)
      fo[(w16 + rgrp + r) * 256 + gt * 16 + l16] = fr[gt][r];
}

// ---------------- launcher ----------------

extern "C" void kernel_launch(void* const* d_in, const int* in_sizes, int n_in,
                              void* d_out, int out_size, void* d_ws, size_t ws_size,
                              hipStream_t stream) {
  const float* coords = (const float*)d_in[0];
  const int* charges = (const int*)d_in[1];
  const int* n_up = (const int*)d_in[3];
  const int* n_down = (const int*)d_in[4];
  const float* nuc_feats = (const float*)d_in[5];
  const float* W_orb = (const float*)d_in[7];
  const float* W_edge = (const float*)d_in[8];
  const float* W_val = (const float*)d_in[9];
  const float* W_nuc = (const float*)d_in[10];
  const float* W_out = (const float*)d_in[11];
  float* out = (float*)d_out;

  char* ws = (char*)d_ws;
  int* orb_nuc = (int*)ws;                                        // 4KB
  int* orb_t = (int*)(ws + 4096);                                 // 4KB
  unsigned short* ewbf = (unsigned short*)(ws + 8192);            // 1MB
  unsigned short* WvTf = (unsigned short*)(ws + 8192 + 1048576);  // 512KB
  unsigned short* WoTf = WvTf + 262144;                           // 512KB
  float* nucbT = (float*)(ws + 8192 + 1048576 + 1048576);         // 512KB

  k_orbmap<<<dim3(1), dim3(256), 0, stream>>>(charges, n_up, n_down, orb_nuc, orb_t);
  k_ew<<<dim3(128), dim3(128), 0, stream>>>(coords, W_edge, ewbf);
  k_wt<<<dim3(1024), dim3(256), 0, stream>>>(W_val, W_out, WvTf, WoTf);
  k_nucbT<<<dim3(512), dim3(256), 0, stream>>>(nuc_feats, W_nuc, nucbT);
  k_main<<<dim3(O_TOT), dim3(512), 0, stream>>>(out, W_orb, WvTf, WoTf, ewbf, nucbT,
                                                orb_nuc, orb_t);
}

// Round 19
// 568.072 us; speedup vs baseline: 1.5098x; 1.1460x over previous
//
#include <hip/hip_runtime.h>
#include <hip/hip_bf16.h>

// OrbitalGenerator: 1024 independent [128x256] slices through a 4-layer MPNN.
// One block per orbital, 512 threads (8 waves). Wave w owns rows w*16..w*16+16.
// R19 = R10 (651us best) + LDS WEIGHT STAGING: the 8 waves previously each
// streamed the same 128KB of WvTf/WoTf per GEMM from L2 (2MB redundant per
// block/layer ~= 40k of the 97k cycles/layer at ~56B/cyc/CU supply). Now each
// GEMM's weights are staged ONCE into a 64KB LDS buffer (WS) per gt-half via
// global_load_lds (width 16, linear dest = fragment-major order), and b-frags
// are conflict-free contiguous ds_read_b128. Wv-half0 staging hides under LN1
// (B1's vmcnt drain); Wo-half0 hides under MSG. Registers/decomposition are
// byte-identical to R10 -> same clean (512,2) regime.

#define O_TOT 1024

typedef __bf16 bf16x8 __attribute__((ext_vector_type(8)));
typedef float f32x4 __attribute__((ext_vector_type(4)));

static __device__ __forceinline__ unsigned short f2bf(float f) {
  __bf16 b = (__bf16)f;
  unsigned short u;
  __builtin_memcpy(&u, &b, 2);
  return u;
}
static __device__ __forceinline__ float ftanh(float x) {
  float e = __expf(2.f * x);
  return 1.f - 2.f * __builtin_amdgcn_rcpf(e + 1.f);
}

struct alignas(8) US4 { unsigned short a, b, c, d; };

// XOR swizzles with 2 row bits -> 16 distinct 16B slots per 16 consecutive rows.
static __device__ __forceinline__ int swzA(int row, int cb) {  // [128][512B]
  return row * 512 + (cb ^ ((row & 7) << 4) ^ (((row >> 3) & 1) << 5));
}
static __device__ __forceinline__ int swzV(int row, int cb) {  // [256][256B]
  return row * 256 + (cb ^ ((row & 7) << 4) ^ (((row >> 3) & 1) << 5));
}

// ---------------- setup kernels (identical to R10) ----------------

__global__ void k_orbmap(const int* __restrict__ charges, const int* __restrict__ n_up_p,
                         const int* __restrict__ n_down_p, int* __restrict__ orb_nuc,
                         int* __restrict__ orb_t) {
  __shared__ int off[129];
  __shared__ int prec[128];
  int tid = threadIdx.x;
  if (tid == 0) {
    int a = 0;
    for (int n = 0; n < 128; ++n) { off[n] = a; a += charges[n]; }
    off[128] = a;
  }
  if (tid < 128) prec[tid] = charges[tid] * (charges[tid] - 1) / 2;
  __syncthreads();
  int nu = *n_up_p, nd = *n_down_p;
  for (int o = tid; o < O_TOT; o += 256) {
    int e;
    if (o < nu) e = o;
    else if (o < 512) e = o + nd;
    else if (o < 512 + nd) e = o + nu - 512;
    else e = o;
    int nn = -1, tt = 0;
    for (int n = 0; n < 128; ++n) {
      if (e >= off[n] && e < off[n + 1]) { nn = n; tt = prec[n] + (e - off[n]); }
    }
    orb_nuc[o] = nn;
    orb_t[o] = tt;
  }
}

// ewbf fragment-major: [l][h][mt(8)][k0(4)][lane(64)][j(8)] bf16 (1MB total).
__global__ void k_ew(const float* __restrict__ coords, const float* __restrict__ W_edge,
                     unsigned short* __restrict__ ewbf) {
  int i = blockIdx.x, j = threadIdx.x;
  float dx = coords[i * 3 + 0] - coords[j * 3 + 0];
  float dy = coords[i * 3 + 1] - coords[j * 3 + 1];
  float dz = coords[i * 3 + 2] - coords[j * 3 + 2];
  float norm = sqrtf(dx * dx + dy * dy + dz * dz + 1e-12f);
  float inv = 1.f / (1.f + norm);
  float e[7];
  e[0] = dx * inv; e[1] = dy * inv; e[2] = dz * inv;
  e[3] = log1pf(norm);
  e[4] = 1.f / (1.f + expf(-(norm - 2.f)));
  e[5] = 1.f / (1.f + expf(-(norm - 4.f)));
  e[6] = 1.f / (1.f + expf(-(norm - 6.f)));
  const int mt = i >> 4, l16 = i & 15;
  const int k0 = j >> 5, jo = j & 31;
  const int lane = (jo >> 3) * 16 + l16, jj = jo & 7;
  for (int l = 0; l < 4; ++l)
    for (int h = 0; h < 8; ++h) {
      float s = 0.f;
      for (int k = 0; k < 7; ++k) s += e[k] * W_edge[(l * 7 + k) * 8 + h];
      ewbf[(((((l * 8 + h) * 8 + mt) * 4 + k0) * 64) + lane) * 8 + jj] = f2bf(s);
    }
}

// WvTf/WoTf fragment-major: [l][gt(16)][k0(8)][lane(64)][jj(8)] bf16.
__global__ void k_wt(const float* __restrict__ Wv, const float* __restrict__ Wo,
                     unsigned short* __restrict__ WvTf, unsigned short* __restrict__ WoTf) {
  int idx = blockIdx.x * 256 + threadIdx.x;  // 4*65536
  const int l = idx >> 16, rem = idx & 65535;
  const int jj = rem & 7, lane = (rem >> 3) & 63, k0 = (rem >> 9) & 7, gt = rem >> 12;
  const int g = gt * 16 + (lane & 15);
  const int f = k0 * 32 + (lane >> 4) * 8 + jj;
  const int src = l * 65536 + f * 256 + g;
  WvTf[idx] = f2bf(Wv[src]);
  WoTf[idx] = f2bf(Wo[src]);
}

// nucbT[l][g][i] = nuc_feats[i,:] @ W_nuc[l][:,g]  (fp32, transposed)
__global__ void k_nucbT(const float* __restrict__ nuc_feats, const float* __restrict__ W_nuc,
                        float* __restrict__ nucbT) {
  int b = blockIdx.x;  // l*128 + i
  int l = b >> 7, i = b & 127;
  int g = threadIdx.x;
  __shared__ float row[256];
  row[g] = nuc_feats[i * 256 + g];
  __syncthreads();
  const float* Wn = W_nuc + l * 65536;
  float s = 0.f;
  for (int f = 0; f < 256; ++f) s += row[f] * Wn[f * 256 + g];
  nucbT[(l * 256 + g) * 128 + i] = s;
}

// ---------------- fused main kernel ----------------

__global__ __launch_bounds__(512, 2) void k_main(
    float* __restrict__ feats,                // d_out [1024][128][256] fp32
    const float* __restrict__ W_orb,          // [136][256]
    const unsigned short* __restrict__ WvTf,  // fragment-major (see k_wt)
    const unsigned short* __restrict__ WoTf,  // fragment-major
    const unsigned short* __restrict__ ewbf,  // fragment-major (see k_ew)
    const float* __restrict__ nucbT,          // [4][256][128] fp32
    const int* __restrict__ orb_nuc, const int* __restrict__ orb_t) {
  __shared__ char SB[65536];       // h -> valsT -> msg (reused via barriers)
  __shared__ char WS[65536];       // staged weight half (64 frags x 1KB, linear)
  __shared__ float2 ln2s[8][128];  // LN2 per-head partials [head][row]{s,ss}
  __shared__ float red[8];

  const int o = blockIdx.x;
  const int tid = threadIdx.x;
  const int wave = tid >> 6;
  const int lane = tid & 63;
  const int l16 = lane & 15;
  const int kgrp = (lane >> 4) << 3;  // A/B fragment k-offset: 0,8,16,24
  const int rgrp = (lane >> 4) << 2;  // D fragment row group: 0,4,8,12
  const int w16 = wave * 16;          // this wave's 16 rows

  const int nn = orb_nuc[o];
  const int tt = orb_t[o];
  float* fo = feats + (size_t)o * 32768;

  // stage 64KB (one gt-half of a weight layer slice) into WS, linear order.
  // 8 sweeps x (512 thr x 16B); wave-uniform LDS base + lane*16 (implicit).
  auto stage64 = [&](const unsigned short* gsrc) {
#pragma unroll
    for (int s = 0; s < 8; ++s)
      __builtin_amdgcn_global_load_lds(
          (const __attribute__((address_space(1))) void*)(gsrc + s * 4096 +
                                                          wave * 512 + lane * 8),
          (__attribute__((address_space(3))) void*)(WS + s * 8192 + wave * 1024),
          16, 0, 0);
  };

  // feats in registers: fr[gt][r] = feats[w16+rgrp+r][gt*16+l16]  (64 regs)
  f32x4 fr[16];
#pragma unroll
  for (int gt = 0; gt < 16; ++gt) {
    f32x4 v = {0.f, 0.f, 0.f, 0.f};
#pragma unroll
    for (int r = 0; r < 4; ++r)
      if (w16 + rgrp + r == nn) v[r] = W_orb[tt * 256 + gt * 16 + l16];
    fr[gt] = v;
  }

#pragma unroll 1
  for (int l = 0; l < 4; ++l) {
    // ---- stage Wv half0 (gt 0..7) — hidden under LN1, ready at B1 ----
    stage64(WvTf + l * 65536);

    // ---- LN1 (wave-local): stats from fr, centered h -> private SB rows,
    //      A-fragments hoisted back (in-wave LDS ordering, no barrier) ----
    bf16x8 A[8];
    {
      float s[4] = {0, 0, 0, 0}, q[4] = {0, 0, 0, 0};
#pragma unroll
      for (int gt = 0; gt < 16; ++gt)
#pragma unroll
        for (int r = 0; r < 4; ++r) {
          float v = fr[gt][r];
          s[r] += v; q[r] += v * v;
        }
#pragma unroll
      for (int of = 1; of < 16; of <<= 1)
#pragma unroll
        for (int r = 0; r < 4; ++r) {
          s[r] += __shfl_xor(s[r], of);
          q[r] += __shfl_xor(q[r], of);
        }
      float mean[4], maxv = 0.f;
#pragma unroll
      for (int r = 0; r < 4; ++r) {
        mean[r] = s[r] * (1.f / 256.f);
        const float var = q[r] * (1.f / 256.f) - mean[r] * mean[r];
        maxv = fmaxf(maxv, var);
      }
      maxv = fmaxf(maxv, __shfl_xor(maxv, 16));
      maxv = fmaxf(maxv, __shfl_xor(maxv, 32));
      if (lane == 0) red[wave] = maxv;
#pragma unroll
      for (int gt = 0; gt < 16; ++gt)
#pragma unroll
        for (int r = 0; r < 4; ++r)
          *(unsigned short*)(SB + swzA(w16 + rgrp + r, (gt * 16 + l16) * 2)) =
              f2bf(fr[gt][r] - mean[r]);
#pragma unroll
      for (int k0 = 0; k0 < 8; ++k0)
        A[k0] = *(const bf16x8*)(SB + swzA(w16 + l16, (k0 * 32 + kgrp) * 2));
    }
    __syncthreads();  // B1: A-frags + red ready; WS(half0) landed; SB reusable

    float rstd;
    {
      float mv = red[0];
#pragma unroll
      for (int w = 1; w < 8; ++w) mv = fmaxf(mv, red[w]);
      rstd = rsqrtf(mv + 1.f);
    }

    // ---- GEMM1 half0: gt 0..7, b from WS (contiguous ds_read_b128) ----
#pragma unroll
    for (int gt = 0; gt < 8; ++gt) {
      f32x4 acc = {0.f, 0.f, 0.f, 0.f};
      bf16x8 b[4];
#pragma unroll
      for (int k0 = 0; k0 < 4; ++k0)
        b[k0] = *(const bf16x8*)(WS + ((gt * 8 + k0) << 10) + lane * 16);
#pragma unroll
      for (int k0 = 0; k0 < 4; ++k0)
        acc = __builtin_amdgcn_mfma_f32_16x16x32_bf16(A[k0], b[k0], acc, 0, 0, 0);
#pragma unroll
      for (int k0 = 0; k0 < 4; ++k0)
        b[k0] = *(const bf16x8*)(WS + ((gt * 8 + k0 + 4) << 10) + lane * 16);
#pragma unroll
      for (int k0 = 0; k0 < 4; ++k0)
        acc = __builtin_amdgcn_mfma_f32_16x16x32_bf16(A[k0 + 4], b[k0], acc, 0, 0, 0);
      const int gg = gt * 16 + l16;
      US4 ov{f2bf(acc[0] * rstd), f2bf(acc[1] * rstd), f2bf(acc[2] * rstd),
             f2bf(acc[3] * rstd)};
      *(US4*)(SB + swzV(gg, (w16 + rgrp) * 2)) = ov;
    }
    __syncthreads();  // B2a: all WS(half0) reads done
    stage64(WvTf + l * 65536 + 32768);  // Wv half1 (gt 8..15)
    __syncthreads();  // B2b: WS(half1) ready

    // ---- GEMM1 half1: gt 8..15 ----
#pragma unroll
    for (int gt = 8; gt < 16; ++gt) {
      f32x4 acc = {0.f, 0.f, 0.f, 0.f};
      bf16x8 b[4];
#pragma unroll
      for (int k0 = 0; k0 < 4; ++k0)
        b[k0] = *(const bf16x8*)(WS + (((gt - 8) * 8 + k0) << 10) + lane * 16);
#pragma unroll
      for (int k0 = 0; k0 < 4; ++k0)
        acc = __builtin_amdgcn_mfma_f32_16x16x32_bf16(A[k0], b[k0], acc, 0, 0, 0);
#pragma unroll
      for (int k0 = 0; k0 < 4; ++k0)
        b[k0] = *(const bf16x8*)(WS + (((gt - 8) * 8 + k0 + 4) << 10) + lane * 16);
#pragma unroll
      for (int k0 = 0; k0 < 4; ++k0)
        acc = __builtin_amdgcn_mfma_f32_16x16x32_bf16(A[k0 + 4], b[k0], acc, 0, 0, 0);
      const int gg = gt * 16 + l16;
      US4 ov{f2bf(acc[0] * rstd), f2bf(acc[1] * rstd), f2bf(acc[2] * rstd),
             f2bf(acc[3] * rstd)};
      *(US4*)(SB + swzV(gg, (w16 + rgrp) * 2)) = ov;
    }
    __syncthreads();  // B2: valsT complete (also: all WS reads done)

    // ---- hoist this head's valsT slice (f-rows wave*32..+32, K=128) ----
    bf16x8 B0[4], B1[4];
#pragma unroll
    for (int k0 = 0; k0 < 4; ++k0) {
      B0[k0] = *(const bf16x8*)(SB + swzV(wave * 32 + l16, (k0 * 32 + kgrp) * 2));
      B1[k0] = *(const bf16x8*)(SB + swzV(wave * 32 + 16 + l16, (k0 * 32 + kgrp) * 2));
    }
    __syncthreads();  // B3: all valsT reads done; SB reusable for msg

    // ---- stage Wo half0 — hidden under the whole MSG phase ----
    stage64(WoTf + l * 65536);

    // ---- MSG: msg[i][f] = sum_j ew[w][i][j]*valsT[f][j] + nucbT[f][i] ----
    {
      const unsigned short* ewh = ewbf + ((l * 8 + wave) * 8 * 4 * 64 * 8) + lane * 8;
      const float* nbT = nucbT + l * 32768;
      const int f0 = wave * 32 + l16;
      const int f1 = f0 + 16;
#pragma unroll
      for (int mt = 0; mt < 8; ++mt) {
        const int i0 = mt * 16;
        f32x4 acc0 = {0.f, 0.f, 0.f, 0.f}, acc1 = {0.f, 0.f, 0.f, 0.f};
        {
          bf16x8 a0 = *(const bf16x8*)(ewh + (mt * 4 + 0) * 512);
          bf16x8 a1 = *(const bf16x8*)(ewh + (mt * 4 + 1) * 512);
          acc0 = __builtin_amdgcn_mfma_f32_16x16x32_bf16(a0, B0[0], acc0, 0, 0, 0);
          acc1 = __builtin_amdgcn_mfma_f32_16x16x32_bf16(a0, B1[0], acc1, 0, 0, 0);
          acc0 = __builtin_amdgcn_mfma_f32_16x16x32_bf16(a1, B0[1], acc0, 0, 0, 0);
          acc1 = __builtin_amdgcn_mfma_f32_16x16x32_bf16(a1, B1[1], acc1, 0, 0, 0);
        }
        {
          bf16x8 a0 = *(const bf16x8*)(ewh + (mt * 4 + 2) * 512);
          bf16x8 a1 = *(const bf16x8*)(ewh + (mt * 4 + 3) * 512);
          acc0 = __builtin_amdgcn_mfma_f32_16x16x32_bf16(a0, B0[2], acc0, 0, 0, 0);
          acc1 = __builtin_amdgcn_mfma_f32_16x16x32_bf16(a0, B1[2], acc1, 0, 0, 0);
          acc0 = __builtin_amdgcn_mfma_f32_16x16x32_bf16(a1, B0[3], acc0, 0, 0, 0);
          acc1 = __builtin_amdgcn_mfma_f32_16x16x32_bf16(a1, B1[3], acc1, 0, 0, 0);
        }
        const f32x4 nb0 = *(const f32x4*)(nbT + f0 * 128 + i0 + rgrp);
        const f32x4 nb1 = *(const f32x4*)(nbT + f1 * 128 + i0 + rgrp);
        float sp[4], qp[4];
#pragma unroll
        for (int r = 0; r < 4; ++r) {
          const float v0 = acc0[r] + nb0[r];
          const float v1 = acc1[r] + nb1[r];
          *(unsigned short*)(SB + swzA(i0 + rgrp + r, f0 * 2)) = f2bf(v0);
          *(unsigned short*)(SB + swzA(i0 + rgrp + r, f1 * 2)) = f2bf(v1);
          sp[r] = v0 + v1;
          qp[r] = v0 * v0 + v1 * v1;
        }
#pragma unroll
        for (int of = 1; of < 16; of <<= 1)
#pragma unroll
          for (int r = 0; r < 4; ++r) {
            sp[r] += __shfl_xor(sp[r], of);
            qp[r] += __shfl_xor(qp[r], of);
          }
        if (l16 == 0) {
#pragma unroll
          for (int r = 0; r < 4; ++r)
            ln2s[wave][i0 + rgrp + r] = float2{sp[r], qp[r]};
        }
      }
    }
    __syncthreads();  // B4: msg + ln2s ready; WS(Wo half0) landed

    // ---- LN2 combine + tanh A2-build + GEMM2 half0 ----
    bf16x8 A2[8];
    {
      float s0 = 0.f, q0 = 0.f, s1v = 0.f, q1v = 0.f;
#pragma unroll
      for (int h = 0; h < 8; ++h) {
        const float2 p0 = ln2s[h][lane];
        const float2 p1 = ln2s[h][lane + 64];
        s0 += p0.x; q0 += p0.y;
        s1v += p1.x; q1v += p1.y;
      }
      const float mean_a = s0 * (1.f / 256.f);
      const float mean_b = s1v * (1.f / 256.f);
      float v0 = q0 * (1.f / 256.f) - mean_a * mean_a;
      float v1 = q1v * (1.f / 256.f) - mean_b * mean_b;
      float mv = fmaxf(v0, v1);
#pragma unroll
      for (int of = 1; of < 64; of <<= 1) mv = fmaxf(mv, __shfl_xor(mv, of));
      const float rstd2 = rsqrtf(mv + 1.f);
      const float meansel = (wave >= 4) ? mean_b : mean_a;
      const float mn = __shfl(meansel, ((wave & 3) << 4) + l16);
#pragma unroll
      for (int k0 = 0; k0 < 8; ++k0) {
        bf16x8 raw = *(const bf16x8*)(SB + swzA(w16 + l16, (k0 * 32 + kgrp) * 2));
        bf16x8 t;
#pragma unroll
        for (int j = 0; j < 8; ++j)
          t[j] = (__bf16)ftanh(((float)raw[j] - mn) * rstd2);
        A2[k0] = t;
      }
    }
#pragma unroll
    for (int gt = 0; gt < 8; ++gt) {
      f32x4 acc = fr[gt];
      bf16x8 b[4];
#pragma unroll
      for (int k0 = 0; k0 < 4; ++k0)
        b[k0] = *(const bf16x8*)(WS + ((gt * 8 + k0) << 10) + lane * 16);
#pragma unroll
      for (int k0 = 0; k0 < 4; ++k0)
        acc = __builtin_amdgcn_mfma_f32_16x16x32_bf16(A2[k0], b[k0], acc, 0, 0, 0);
#pragma unroll
      for (int k0 = 0; k0 < 4; ++k0)
        b[k0] = *(const bf16x8*)(WS + ((gt * 8 + k0 + 4) << 10) + lane * 16);
#pragma unroll
      for (int k0 = 0; k0 < 4; ++k0)
        acc = __builtin_amdgcn_mfma_f32_16x16x32_bf16(A2[k0 + 4], b[k0], acc, 0, 0, 0);
      fr[gt] = acc;
    }
    __syncthreads();  // B5a: all WS(Wo half0) reads done
    stage64(WoTf + l * 65536 + 32768);  // Wo half1
    __syncthreads();  // B5b: WS(half1) ready

    // ---- GEMM2 half1: gt 8..15 ----
#pragma unroll
    for (int gt = 8; gt < 16; ++gt) {
      f32x4 acc = fr[gt];
      bf16x8 b[4];
#pragma unroll
      for (int k0 = 0; k0 < 4; ++k0)
        b[k0] = *(const bf16x8*)(WS + (((gt - 8) * 8 + k0) << 10) + lane * 16);
#pragma unroll
      for (int k0 = 0; k0 < 4; ++k0)
        acc = __builtin_amdgcn_mfma_f32_16x16x32_bf16(A2[k0], b[k0], acc, 0, 0, 0);
#pragma unroll
      for (int k0 = 0; k0 < 4; ++k0)
        b[k0] = *(const bf16x8*)(WS + (((gt - 8) * 8 + k0 + 4) << 10) + lane * 16);
#pragma unroll
      for (int k0 = 0; k0 < 4; ++k0)
        acc = __builtin_amdgcn_mfma_f32_16x16x32_bf16(A2[k0 + 4], b[k0], acc, 0, 0, 0);
      fr[gt] = acc;
    }
    __syncthreads();  // B6: all WS reads done before next layer's stage64
  }

  // ---- final store: direct from fr (64B segments per l16 group) ----
#pragma unroll
  for (int gt = 0; gt < 16; ++gt)
#pragma unroll
    for (int r = 0; r < 4; ++r)
      fo[(w16 + rgrp + r) * 256 + gt * 16 + l16] = fr[gt][r];
}

// ---------------- launcher ----------------

extern "C" void kernel_launch(void* const* d_in, const int* in_sizes, int n_in,
                              void* d_out, int out_size, void* d_ws, size_t ws_size,
                              hipStream_t stream) {
  const float* coords = (const float*)d_in[0];
  const int* charges = (const int*)d_in[1];
  const int* n_up = (const int*)d_in[3];
  const int* n_down = (const int*)d_in[4];
  const float* nuc_feats = (const float*)d_in[5];
  const float* W_orb = (const float*)d_in[7];
  const float* W_edge = (const float*)d_in[8];
  const float* W_val = (const float*)d_in[9];
  const float* W_nuc = (const float*)d_in[10];
  const float* W_out = (const float*)d_in[11];
  float* out = (float*)d_out;

  char* ws = (char*)d_ws;
  int* orb_nuc = (int*)ws;                                        // 4KB
  int* orb_t = (int*)(ws + 4096);                                 // 4KB
  unsigned short* ewbf = (unsigned short*)(ws + 8192);            // 1MB
  unsigned short* WvTf = (unsigned short*)(ws + 8192 + 1048576);  // 512KB
  unsigned short* WoTf = WvTf + 262144;                           // 512KB
  float* nucbT = (float*)(ws + 8192 + 1048576 + 1048576);         // 512KB

  k_orbmap<<<dim3(1), dim3(256), 0, stream>>>(charges, n_up, n_down, orb_nuc, orb_t);
  k_ew<<<dim3(128), dim3(128), 0, stream>>>(coords, W_edge, ewbf);
  k_wt<<<dim3(1024), dim3(256), 0, stream>>>(W_val, W_out, WvTf, WoTf);
  k_nucbT<<<dim3(512), dim3(256), 0, stream>>>(nuc_feats, W_nuc, nucbT);
  k_main<<<dim3(O_TOT), dim3(512), 0, stream>>>(out, W_orb, WvTf, WoTf, ewbf, nucbT,
                                                orb_nuc, orb_t);
}

// Round 20
// 523.039 us; speedup vs baseline: 1.6397x; 1.0861x over previous
//
#include <hip/hip_runtime.h>
#include <hip/hip_bf16.h>

// OrbitalGenerator: 1024 independent [128x256] slices through a 4-layer MPNN.
// One block per orbital, 512 threads (8 waves). Wave w owns rows w*16..w*16+16.
// R20 = R19 (568us: LDS weight staging dedup) + supply-side refinements:
//  1) nucbT stored bf16 (-256KB/block L2 traffic, half-size MSG bias loads)
//  2) quarter-pipelined staging: WS = 2x32KB ping-pong; quarter q+1 stages
//     while quarter q computes -> the two exposed 64KB stages per layer are
//     fully hidden (cost: +2 barriers/layer).
// Register regime byte-identical to R19: (512,2), fr[16] f32x4 in AGPR.

#define O_TOT 1024

typedef __bf16 bf16x8 __attribute__((ext_vector_type(8)));
typedef __bf16 bf16x4 __attribute__((ext_vector_type(4)));
typedef float f32x4 __attribute__((ext_vector_type(4)));

static __device__ __forceinline__ unsigned short f2bf(float f) {
  __bf16 b = (__bf16)f;
  unsigned short u;
  __builtin_memcpy(&u, &b, 2);
  return u;
}
static __device__ __forceinline__ float ftanh(float x) {
  float e = __expf(2.f * x);
  return 1.f - 2.f * __builtin_amdgcn_rcpf(e + 1.f);
}

struct alignas(8) US4 { unsigned short a, b, c, d; };

// XOR swizzles with 2 row bits -> 16 distinct 16B slots per 16 consecutive rows.
static __device__ __forceinline__ int swzA(int row, int cb) {  // [128][512B]
  return row * 512 + (cb ^ ((row & 7) << 4) ^ (((row >> 3) & 1) << 5));
}
static __device__ __forceinline__ int swzV(int row, int cb) {  // [256][256B]
  return row * 256 + (cb ^ ((row & 7) << 4) ^ (((row >> 3) & 1) << 5));
}

// ---------------- setup kernels ----------------

__global__ void k_orbmap(const int* __restrict__ charges, const int* __restrict__ n_up_p,
                         const int* __restrict__ n_down_p, int* __restrict__ orb_nuc,
                         int* __restrict__ orb_t) {
  __shared__ int off[129];
  __shared__ int prec[128];
  int tid = threadIdx.x;
  if (tid == 0) {
    int a = 0;
    for (int n = 0; n < 128; ++n) { off[n] = a; a += charges[n]; }
    off[128] = a;
  }
  if (tid < 128) prec[tid] = charges[tid] * (charges[tid] - 1) / 2;
  __syncthreads();
  int nu = *n_up_p, nd = *n_down_p;
  for (int o = tid; o < O_TOT; o += 256) {
    int e;
    if (o < nu) e = o;
    else if (o < 512) e = o + nd;
    else if (o < 512 + nd) e = o + nu - 512;
    else e = o;
    int nn = -1, tt = 0;
    for (int n = 0; n < 128; ++n) {
      if (e >= off[n] && e < off[n + 1]) { nn = n; tt = prec[n] + (e - off[n]); }
    }
    orb_nuc[o] = nn;
    orb_t[o] = tt;
  }
}

// ewbf fragment-major: [l][h][mt(8)][k0(4)][lane(64)][j(8)] bf16 (1MB total).
__global__ void k_ew(const float* __restrict__ coords, const float* __restrict__ W_edge,
                     unsigned short* __restrict__ ewbf) {
  int i = blockIdx.x, j = threadIdx.x;
  float dx = coords[i * 3 + 0] - coords[j * 3 + 0];
  float dy = coords[i * 3 + 1] - coords[j * 3 + 1];
  float dz = coords[i * 3 + 2] - coords[j * 3 + 2];
  float norm = sqrtf(dx * dx + dy * dy + dz * dz + 1e-12f);
  float inv = 1.f / (1.f + norm);
  float e[7];
  e[0] = dx * inv; e[1] = dy * inv; e[2] = dz * inv;
  e[3] = log1pf(norm);
  e[4] = 1.f / (1.f + expf(-(norm - 2.f)));
  e[5] = 1.f / (1.f + expf(-(norm - 4.f)));
  e[6] = 1.f / (1.f + expf(-(norm - 6.f)));
  const int mt = i >> 4, l16 = i & 15;
  const int k0 = j >> 5, jo = j & 31;
  const int lane = (jo >> 3) * 16 + l16, jj = jo & 7;
  for (int l = 0; l < 4; ++l)
    for (int h = 0; h < 8; ++h) {
      float s = 0.f;
      for (int k = 0; k < 7; ++k) s += e[k] * W_edge[(l * 7 + k) * 8 + h];
      ewbf[(((((l * 8 + h) * 8 + mt) * 4 + k0) * 64) + lane) * 8 + jj] = f2bf(s);
    }
}

// WvTf/WoTf fragment-major: [l][gt(16)][k0(8)][lane(64)][jj(8)] bf16.
__global__ void k_wt(const float* __restrict__ Wv, const float* __restrict__ Wo,
                     unsigned short* __restrict__ WvTf, unsigned short* __restrict__ WoTf) {
  int idx = blockIdx.x * 256 + threadIdx.x;  // 4*65536
  const int l = idx >> 16, rem = idx & 65535;
  const int jj = rem & 7, lane = (rem >> 3) & 63, k0 = (rem >> 9) & 7, gt = rem >> 12;
  const int g = gt * 16 + (lane & 15);
  const int f = k0 * 32 + (lane >> 4) * 8 + jj;
  const int src = l * 65536 + f * 256 + g;
  WvTf[idx] = f2bf(Wv[src]);
  WoTf[idx] = f2bf(Wo[src]);
}

// nucbTb[l][g][i] = bf16( nuc_feats[i,:] @ W_nuc[l][:,g] )  (transposed, bf16)
__global__ void k_nucbT(const float* __restrict__ nuc_feats, const float* __restrict__ W_nuc,
                        unsigned short* __restrict__ nucbTb) {
  int b = blockIdx.x;  // l*128 + i
  int l = b >> 7, i = b & 127;
  int g = threadIdx.x;
  __shared__ float row[256];
  row[g] = nuc_feats[i * 256 + g];
  __syncthreads();
  const float* Wn = W_nuc + l * 65536;
  float s = 0.f;
  for (int f = 0; f < 256; ++f) s += row[f] * Wn[f * 256 + g];
  nucbTb[(l * 256 + g) * 128 + i] = f2bf(s);
}

// ---------------- fused main kernel ----------------

__global__ __launch_bounds__(512, 2) void k_main(
    float* __restrict__ feats,                // d_out [1024][128][256] fp32
    const float* __restrict__ W_orb,          // [136][256]
    const unsigned short* __restrict__ WvTf,  // fragment-major (see k_wt)
    const unsigned short* __restrict__ WoTf,  // fragment-major
    const unsigned short* __restrict__ ewbf,  // fragment-major (see k_ew)
    const unsigned short* __restrict__ nucbTb,  // [4][256][128] bf16
    const int* __restrict__ orb_nuc, const int* __restrict__ orb_t) {
  __shared__ char SB[65536];       // h -> valsT -> msg (reused via barriers)
  __shared__ char WS[65536];       // 2 x 32KB ping-pong weight quarters
  __shared__ float2 ln2s[8][128];  // LN2 per-head partials [head][row]{s,ss}
  __shared__ float red[8];

  const int o = blockIdx.x;
  const int tid = threadIdx.x;
  const int wave = tid >> 6;
  const int lane = tid & 63;
  const int l16 = lane & 15;
  const int kgrp = (lane >> 4) << 3;  // A/B fragment k-offset: 0,8,16,24
  const int rgrp = (lane >> 4) << 2;  // D fragment row group: 0,4,8,12
  const int w16 = wave * 16;          // this wave's 16 rows

  const int nn = orb_nuc[o];
  const int tt = orb_t[o];
  float* fo = feats + (size_t)o * 32768;

  // stage 32KB (one weight quarter = 32 frags) into dst, linear order.
  auto stage32 = [&](char* dst, const unsigned short* gsrc) {
#pragma unroll
    for (int s = 0; s < 4; ++s)
      __builtin_amdgcn_global_load_lds(
          (const __attribute__((address_space(1))) void*)(gsrc + s * 4096 +
                                                          wave * 512 + lane * 8),
          (__attribute__((address_space(3))) void*)(dst + s * 8192 + wave * 1024),
          16, 0, 0);
  };

  // feats in registers: fr[gt][r] = feats[w16+rgrp+r][gt*16+l16]  (64 regs)
  f32x4 fr[16];
#pragma unroll
  for (int gt = 0; gt < 16; ++gt) {
    f32x4 v = {0.f, 0.f, 0.f, 0.f};
#pragma unroll
    for (int r = 0; r < 4; ++r)
      if (w16 + rgrp + r == nn) v[r] = W_orb[tt * 256 + gt * 16 + l16];
    fr[gt] = v;
  }

#pragma unroll 1
  for (int l = 0; l < 4; ++l) {
    const unsigned short* Wvl = WvTf + l * 65536;
    const unsigned short* Wol = WoTf + l * 65536;

    // ---- stage Wv q0,q1 (gt 0..7) — hidden under LN1, drained at B1 ----
    stage32(WS, Wvl);
    stage32(WS + 32768, Wvl + 16384);

    // ---- LN1 (wave-local): stats from fr, centered h -> private SB rows,
    //      A-fragments hoisted back (in-wave LDS ordering, no barrier) ----
    bf16x8 A[8];
    {
      float s[4] = {0, 0, 0, 0}, q[4] = {0, 0, 0, 0};
#pragma unroll
      for (int gt = 0; gt < 16; ++gt)
#pragma unroll
        for (int r = 0; r < 4; ++r) {
          float v = fr[gt][r];
          s[r] += v; q[r] += v * v;
        }
#pragma unroll
      for (int of = 1; of < 16; of <<= 1)
#pragma unroll
        for (int r = 0; r < 4; ++r) {
          s[r] += __shfl_xor(s[r], of);
          q[r] += __shfl_xor(q[r], of);
        }
      float mean[4], maxv = 0.f;
#pragma unroll
      for (int r = 0; r < 4; ++r) {
        mean[r] = s[r] * (1.f / 256.f);
        const float var = q[r] * (1.f / 256.f) - mean[r] * mean[r];
        maxv = fmaxf(maxv, var);
      }
      maxv = fmaxf(maxv, __shfl_xor(maxv, 16));
      maxv = fmaxf(maxv, __shfl_xor(maxv, 32));
      if (lane == 0) red[wave] = maxv;
#pragma unroll
      for (int gt = 0; gt < 16; ++gt)
#pragma unroll
        for (int r = 0; r < 4; ++r)
          *(unsigned short*)(SB + swzA(w16 + rgrp + r, (gt * 16 + l16) * 2)) =
              f2bf(fr[gt][r] - mean[r]);
#pragma unroll
      for (int k0 = 0; k0 < 8; ++k0)
        A[k0] = *(const bf16x8*)(SB + swzA(w16 + l16, (k0 * 32 + kgrp) * 2));
    }
    __syncthreads();  // B1: A-frags + red ready; Wv q0,q1 landed; SB reusable

    float rstd;
    {
      float mv = red[0];
#pragma unroll
      for (int w = 1; w < 8; ++w) mv = fmaxf(mv, red[w]);
      rstd = rsqrtf(mv + 1.f);
    }

    // GEMM1 quarter macro: gt in [g0,g0+4), frags from buf
#define G1Q(g0, buf)                                                              \
  {                                                                               \
    _Pragma("unroll") for (int gt = (g0); gt < (g0) + 4; ++gt) {                  \
      f32x4 acc = {0.f, 0.f, 0.f, 0.f};                                           \
      bf16x8 b[4];                                                                \
      _Pragma("unroll") for (int k0 = 0; k0 < 4; ++k0) b[k0] =                    \
          *(const bf16x8*)((buf) + (((gt - (g0)) * 8 + k0) << 10) + lane * 16);   \
      _Pragma("unroll") for (int k0 = 0; k0 < 4; ++k0) acc =                      \
          __builtin_amdgcn_mfma_f32_16x16x32_bf16(A[k0], b[k0], acc, 0, 0, 0);    \
      _Pragma("unroll") for (int k0 = 0; k0 < 4; ++k0) b[k0] =                    \
          *(const bf16x8*)((buf) + (((gt - (g0)) * 8 + k0 + 4) << 10) +           \
                           lane * 16);                                            \
      _Pragma("unroll") for (int k0 = 0; k0 < 4; ++k0) acc =                      \
          __builtin_amdgcn_mfma_f32_16x16x32_bf16(A[k0 + 4], b[k0], acc, 0, 0, 0);\
      const int gg = gt * 16 + l16;                                               \
      US4 ov{f2bf(acc[0] * rstd), f2bf(acc[1] * rstd), f2bf(acc[2] * rstd),       \
             f2bf(acc[3] * rstd)};                                                \
      *(US4*)(SB + swzV(gg, (w16 + rgrp) * 2)) = ov;                              \
    }                                                                             \
  }

    G1Q(0, WS)
    __syncthreads();  // Bg1: WS(q0) reads done
    stage32(WS, Wvl + 32768);  // q2 (gt 8..11) overlaps q1 compute
    G1Q(4, WS + 32768)
    __syncthreads();  // Bg2: q2 drained + WS1(q1) reads done
    stage32(WS + 32768, Wvl + 49152);  // q3 overlaps q2 compute
    G1Q(8, WS)
    __syncthreads();  // Bg3: q3 drained + WS(q2) reads done
    G1Q(12, WS + 32768)
    __syncthreads();  // Bv: valsT complete
#undef G1Q

    // ---- hoist this head's valsT slice (f-rows wave*32..+32, K=128) ----
    bf16x8 B0[4], B1[4];
#pragma unroll
    for (int k0 = 0; k0 < 4; ++k0) {
      B0[k0] = *(const bf16x8*)(SB + swzV(wave * 32 + l16, (k0 * 32 + kgrp) * 2));
      B1[k0] = *(const bf16x8*)(SB + swzV(wave * 32 + 16 + l16, (k0 * 32 + kgrp) * 2));
    }
    __syncthreads();  // Bh: valsT reads done; SB reusable; WS reads all done

    // ---- stage Wo q0,q1 — hidden under the whole MSG phase ----
    stage32(WS, Wol);
    stage32(WS + 32768, Wol + 16384);

    // ---- MSG: msg[i][f] = sum_j ew[w][i][j]*valsT[f][j] + nucbT[f][i] ----
    {
      const unsigned short* ewh = ewbf + ((l * 8 + wave) * 8 * 4 * 64 * 8) + lane * 8;
      const unsigned short* nbT = nucbTb + l * 32768;
      const int f0 = wave * 32 + l16;
      const int f1 = f0 + 16;
#pragma unroll
      for (int mt = 0; mt < 8; ++mt) {
        const int i0 = mt * 16;
        f32x4 acc0 = {0.f, 0.f, 0.f, 0.f}, acc1 = {0.f, 0.f, 0.f, 0.f};
        {
          bf16x8 a0 = *(const bf16x8*)(ewh + (mt * 4 + 0) * 512);
          bf16x8 a1 = *(const bf16x8*)(ewh + (mt * 4 + 1) * 512);
          acc0 = __builtin_amdgcn_mfma_f32_16x16x32_bf16(a0, B0[0], acc0, 0, 0, 0);
          acc1 = __builtin_amdgcn_mfma_f32_16x16x32_bf16(a0, B1[0], acc1, 0, 0, 0);
          acc0 = __builtin_amdgcn_mfma_f32_16x16x32_bf16(a1, B0[1], acc0, 0, 0, 0);
          acc1 = __builtin_amdgcn_mfma_f32_16x16x32_bf16(a1, B1[1], acc1, 0, 0, 0);
        }
        {
          bf16x8 a0 = *(const bf16x8*)(ewh + (mt * 4 + 2) * 512);
          bf16x8 a1 = *(const bf16x8*)(ewh + (mt * 4 + 3) * 512);
          acc0 = __builtin_amdgcn_mfma_f32_16x16x32_bf16(a0, B0[2], acc0, 0, 0, 0);
          acc1 = __builtin_amdgcn_mfma_f32_16x16x32_bf16(a0, B1[2], acc1, 0, 0, 0);
          acc0 = __builtin_amdgcn_mfma_f32_16x16x32_bf16(a1, B0[3], acc0, 0, 0, 0);
          acc1 = __builtin_amdgcn_mfma_f32_16x16x32_bf16(a1, B1[3], acc1, 0, 0, 0);
        }
        const bf16x4 nb0 = *(const bf16x4*)(nbT + f0 * 128 + i0 + rgrp);
        const bf16x4 nb1 = *(const bf16x4*)(nbT + f1 * 128 + i0 + rgrp);
        float sp[4], qp[4];
#pragma unroll
        for (int r = 0; r < 4; ++r) {
          const float v0 = acc0[r] + (float)nb0[r];
          const float v1 = acc1[r] + (float)nb1[r];
          *(unsigned short*)(SB + swzA(i0 + rgrp + r, f0 * 2)) = f2bf(v0);
          *(unsigned short*)(SB + swzA(i0 + rgrp + r, f1 * 2)) = f2bf(v1);
          sp[r] = v0 + v1;
          qp[r] = v0 * v0 + v1 * v1;
        }
#pragma unroll
        for (int of = 1; of < 16; of <<= 1)
#pragma unroll
          for (int r = 0; r < 4; ++r) {
            sp[r] += __shfl_xor(sp[r], of);
            qp[r] += __shfl_xor(qp[r], of);
          }
        if (l16 == 0) {
#pragma unroll
          for (int r = 0; r < 4; ++r)
            ln2s[wave][i0 + rgrp + r] = float2{sp[r], qp[r]};
        }
      }
    }
    __syncthreads();  // B4: msg + ln2s ready; Wo q0,q1 landed

    // ---- LN2 combine + tanh A2-build ----
    bf16x8 A2[8];
    {
      float s0 = 0.f, q0 = 0.f, s1v = 0.f, q1v = 0.f;
#pragma unroll
      for (int h = 0; h < 8; ++h) {
        const float2 p0 = ln2s[h][lane];
        const float2 p1 = ln2s[h][lane + 64];
        s0 += p0.x; q0 += p0.y;
        s1v += p1.x; q1v += p1.y;
      }
      const float mean_a = s0 * (1.f / 256.f);
      const float mean_b = s1v * (1.f / 256.f);
      float v0 = q0 * (1.f / 256.f) - mean_a * mean_a;
      float v1 = q1v * (1.f / 256.f) - mean_b * mean_b;
      float mv = fmaxf(v0, v1);
#pragma unroll
      for (int of = 1; of < 64; of <<= 1) mv = fmaxf(mv, __shfl_xor(mv, of));
      const float rstd2 = rsqrtf(mv + 1.f);
      const float meansel = (wave >= 4) ? mean_b : mean_a;
      const float mn = __shfl(meansel, ((wave & 3) << 4) + l16);
#pragma unroll
      for (int k0 = 0; k0 < 8; ++k0) {
        bf16x8 raw = *(const bf16x8*)(SB + swzA(w16 + l16, (k0 * 32 + kgrp) * 2));
        bf16x8 t;
#pragma unroll
        for (int j = 0; j < 8; ++j)
          t[j] = (__bf16)ftanh(((float)raw[j] - mn) * rstd2);
        A2[k0] = t;
      }
    }

    // GEMM2 quarter macro: gt in [g0,g0+4), acc seeded from fr
#define G2Q(g0, buf)                                                              \
  {                                                                               \
    _Pragma("unroll") for (int gt = (g0); gt < (g0) + 4; ++gt) {                  \
      f32x4 acc = fr[gt];                                                         \
      bf16x8 b[4];                                                                \
      _Pragma("unroll") for (int k0 = 0; k0 < 4; ++k0) b[k0] =                    \
          *(const bf16x8*)((buf) + (((gt - (g0)) * 8 + k0) << 10) + lane * 16);   \
      _Pragma("unroll") for (int k0 = 0; k0 < 4; ++k0) acc =                      \
          __builtin_amdgcn_mfma_f32_16x16x32_bf16(A2[k0], b[k0], acc, 0, 0, 0);   \
      _Pragma("unroll") for (int k0 = 0; k0 < 4; ++k0) b[k0] =                    \
          *(const bf16x8*)((buf) + (((gt - (g0)) * 8 + k0 + 4) << 10) +           \
                           lane * 16);                                            \
      _Pragma("unroll") for (int k0 = 0; k0 < 4; ++k0) acc =                      \
          __builtin_amdgcn_mfma_f32_16x16x32_bf16(A2[k0 + 4], b[k0], acc, 0, 0, 0);\
      fr[gt] = acc;                                                               \
    }                                                                             \
  }

    G2Q(0, WS)
    __syncthreads();  // Bo1: WS(q0) reads done
    stage32(WS, Wol + 32768);  // q2 overlaps q1 compute
    G2Q(4, WS + 32768)
    __syncthreads();  // Bo2: q2 drained + WS1(q1) reads done
    stage32(WS + 32768, Wol + 49152);  // q3 overlaps q2 compute
    G2Q(8, WS)
    __syncthreads();  // Bo3: q3 drained + WS(q2) reads done
    G2Q(12, WS + 32768)
    __syncthreads();  // Bend: WS reads done before next layer's stages
#undef G2Q
  }

  // ---- final store: direct from fr (64B segments per l16 group) ----
#pragma unroll
  for (int gt = 0; gt < 16; ++gt)
#pragma unroll
    for (int r = 0; r < 4; ++r)
      fo[(w16 + rgrp + r) * 256 + gt * 16 + l16] = fr[gt][r];
}

// ---------------- launcher ----------------

extern "C" void kernel_launch(void* const* d_in, const int* in_sizes, int n_in,
                              void* d_out, int out_size, void* d_ws, size_t ws_size,
                              hipStream_t stream) {
  const float* coords = (const float*)d_in[0];
  const int* charges = (const int*)d_in[1];
  const int* n_up = (const int*)d_in[3];
  const int* n_down = (const int*)d_in[4];
  const float* nuc_feats = (const float*)d_in[5];
  const float* W_orb = (const float*)d_in[7];
  const float* W_edge = (const float*)d_in[8];
  const float* W_val = (const float*)d_in[9];
  const float* W_nuc = (const float*)d_in[10];
  const float* W_out = (const float*)d_in[11];
  float* out = (float*)d_out;

  char* ws = (char*)d_ws;
  int* orb_nuc = (int*)ws;                                        // 4KB
  int* orb_t = (int*)(ws + 4096);                                 // 4KB
  unsigned short* ewbf = (unsigned short*)(ws + 8192);            // 1MB
  unsigned short* WvTf = (unsigned short*)(ws + 8192 + 1048576);  // 512KB
  unsigned short* WoTf = WvTf + 262144;                           // 512KB
  unsigned short* nucbTb = (unsigned short*)(ws + 8192 + 1048576 + 1048576);  // 256KB

  k_orbmap<<<dim3(1), dim3(256), 0, stream>>>(charges, n_up, n_down, orb_nuc, orb_t);
  k_ew<<<dim3(128), dim3(128), 0, stream>>>(coords, W_edge, ewbf);
  k_wt<<<dim3(1024), dim3(256), 0, stream>>>(W_val, W_out, WvTf, WoTf);
  k_nucbT<<<dim3(512), dim3(256), 0, stream>>>(nuc_feats, W_nuc, nucbTb);
  k_main<<<dim3(O_TOT), dim3(512), 0, stream>>>(out, W_orb, WvTf, WoTf, ewbf, nucbTb,
                                                orb_nuc, orb_t);
}